// Round 6
// baseline (315.535 us; speedup 1.0000x reference)
//
#include <hip/hip_runtime.h>
#include <cstdint>

typedef short bf16x8 __attribute__((ext_vector_type(8)));
typedef float f32x4  __attribute__((ext_vector_type(4)));

#define TOK    32         // tokens per block (grid 1024 -> 4 blocks/CU)
#define PITCH  264        // ushorts/row (256 + 8 pad)
#define CROWS  32         // codes per chunk per K-half
#define MAXC   32

__device__ __forceinline__ unsigned short f2bf(float f) {
  unsigned u = __float_as_uint(f);
  return (unsigned short)((u + 0x7FFFu + ((u >> 16) & 1u)) >> 16);
}
__device__ __forceinline__ uint4 pack8(float4 a, float4 b) {
  uint4 u;
  u.x = (unsigned)f2bf(a.x) | ((unsigned)f2bf(a.y) << 16);
  u.y = (unsigned)f2bf(a.z) | ((unsigned)f2bf(a.w) << 16);
  u.z = (unsigned)f2bf(b.x) | ((unsigned)f2bf(b.y) << 16);
  u.w = (unsigned)f2bf(b.z) | ((unsigned)f2bf(b.w) << 16);
  return u;
}

// ---------------------------------------------------------------------------
// Prep: cb_bf = bf16(cb), ee = ||cb_k||^2. Block 0 zeroes global accumulators.
// ---------------------------------------------------------------------------
__global__ __launch_bounds__(256) void vq_prep(const float* __restrict__ cb,
                                               unsigned short* __restrict__ cb_bf,
                                               float* __restrict__ ee,
                                               float* __restrict__ acc2,
                                               int* __restrict__ done_ctr, int K) {
  if (blockIdx.x == 0 && threadIdx.x == 0) {
    acc2[0] = 0.f; acc2[1] = 0.f; *done_ctr = 0;
  }
  int wave = threadIdx.x >> 6, lane = threadIdx.x & 63;
  int k = blockIdx.x * 4 + wave;
  if (k >= K) return;
  float4 v = *reinterpret_cast<const float4*>(cb + (size_t)k * 256 + lane * 4);
  float s = v.x * v.x + v.y * v.y + v.z * v.z + v.w * v.w;
  #pragma unroll
  for (int off = 32; off; off >>= 1) s += __shfl_down(s, off, 64);
  ushort4 b;
  b.x = f2bf(v.x); b.y = f2bf(v.y); b.z = f2bf(v.z); b.w = f2bf(v.w);
  *reinterpret_cast<ushort4*>(cb_bf + (size_t)k * 256 + lane * 4) = b;
  if (lane == 0) ee[k] = s;
}

// ---------------------------------------------------------------------------
// Main: 256 thr (4 waves), TOK=32, grid 1024. LDS ~36.2 KB -> 4 blocks/CU
// = 16 waves/CU = 4 waves/SIMD (2x R5's TLP). Evidence R0..R5: kernel is
// latency-bound with every pipe <20%; staging mechanics (serial / reg-
// prefetch / async-DMA) are all equivalent -> TLP is the remaining lever,
// and grid 512 structurally caps at 2 blocks/CU (R2 lesson). TOK=32 doubles
// the grid; LDS diet (chunk=32/half, ee in global, PITCH layout back for
// low bank conflicts) fits 4 blocks/CU.
// Wave (ts = wv&1, kh = wv>>1): tokens [16ts,16ts+16) as 1 A-set in regs,
// K-half kh (512 codes = 16 chunks of 32). Single-buffered reg staging
// (R0 pattern): exposed latency is covered by the 3 other resident blocks.
// Numerics: per-half running amin, margin 1.5, ushort cand MAXC=32, exact
// fp32 rescore (R5 ILP form), exact-scan fallback. UNCHANGED knife-edge.
// DO NOT: 512-thread blocks (VGPR crush + spill); big register prefetch
// arrays (R3 spill); MAXC<32 or looser margin (R2: 4x straggler blowup).
// ---------------------------------------------------------------------------
__global__ __launch_bounds__(256, 4) void vq_main(
    const float* __restrict__ z, const float* __restrict__ cb,
    const unsigned short* __restrict__ cb_bf, const float* __restrict__ ee,
    const float* __restrict__ mask,
    float* __restrict__ out_q, float* __restrict__ out_idx_f,
    float* __restrict__ out_loss, float* __restrict__ acc2,
    int* __restrict__ done_ctr, int nblocks, int K) {
  __shared__ __align__(16) unsigned short buf[64 * PITCH];   // 33792 B: z-stage, then 2x32-row chunk bufs
  __shared__ float znorm[TOK];
  __shared__ int   ccnt[TOK];
  __shared__ unsigned short cand[TOK * MAXC];                // 2 KB
  __shared__ unsigned short bkbuf[TOK];
  __shared__ float red[8];
  __shared__ bool  last;

  const int t = threadIdx.x;
  const int n0 = blockIdx.x * TOK;
  const int wv = t >> 6, lane = t & 63;
  const int ts = wv & 1, kh = wv >> 1;
  const int quad = lane >> 4, l15 = lane & 15;
  const int q16 = t & 15;

  if (t < TOK) ccnt[t] = 0;

  // ---- stage z -> bf16 into buf rows 0..31; ||z|| ----
  #pragma unroll
  for (int pass = 0; pass < 2; ++pass) {
    int row = pass * 16 + (t >> 4);
    const float* zr = z + (size_t)(n0 + row) * 256;
    float ssq = 0.f;
    #pragma unroll
    for (int j = 0; j < 2; ++j) {
      float4 a = *reinterpret_cast<const float4*>(zr + q16 * 8 + j * 128);
      float4 b = *reinterpret_cast<const float4*>(zr + q16 * 8 + j * 128 + 4);
      ssq += a.x*a.x + a.y*a.y + a.z*a.z + a.w*a.w
           + b.x*b.x + b.y*b.y + b.z*b.z + b.w*b.w;
      *reinterpret_cast<uint4*>(&buf[row * PITCH + q16 * 8 + j * 128]) = pack8(a, b);
    }
    #pragma unroll
    for (int off = 1; off < 16; off <<= 1) ssq += __shfl_xor(ssq, off, 64);
    if (q16 == 0) znorm[row] = sqrtf(ssq);
  }
  __syncthreads();  // S1: z staged

  // ---- A fragments into registers: wave owns token rows ts*16 + l15 ----
  bf16x8 afrag[8];
  float  znreg[4];
  {
    const unsigned short* za = &buf[(ts * 16 + l15) * PITCH + quad * 8];
    #pragma unroll
    for (int kk = 0; kk < 8; ++kk)
      afrag[kk] = *reinterpret_cast<const bf16x8*>(za + kk * 32);
    #pragma unroll
    for (int r = 0; r < 4; ++r)
      znreg[r] = znorm[ts * 16 + quad * 4 + r];
  }
  __syncthreads();  // S2: all A-loads done before chunk staging overwrites buf

  // half-group staging identity: 128 threads (both ts-waves of this K-half)
  const int tq = t & 127;
  const int sq16 = tq & 15, srow = tq >> 4;   // 16 lanes/row, 8 rows/pass
  unsigned short* qbuf = &buf[kh * CROWS * PITCH];
  const unsigned short* cbh = cb_bf + (size_t)kh * 512 * 256;

  float amin[4] = {3.4e38f, 3.4e38f, 3.4e38f, 3.4e38f};

  // ---- chunk loop: 16 chunks x 32 codes per K-half, single-buffered ----
  for (int lc = 0; lc < 16; ++lc) {
    const int kbase = kh * 512 + lc * CROWS;
    // stage: 32 rows x 512 B via 128 threads (R0 reg-pair pattern)
    #pragma unroll
    for (int pass = 0; pass < 4; ++pass) {
      int row = pass * 8 + srow;
      const unsigned short* src = cbh + (size_t)(lc * CROWS + row) * 256 + sq16 * 8;
      uint4 v0 = *reinterpret_cast<const uint4*>(src);
      uint4 v1 = *reinterpret_cast<const uint4*>(src + 128);
      *reinterpret_cast<uint4*>(&qbuf[row * PITCH + sq16 * 8])       = v0;
      *reinterpret_cast<uint4*>(&qbuf[row * PITCH + sq16 * 8 + 128]) = v1;
    }
    __syncthreads();  // chunk staged

    // hoist ee loads (L1-resident) so their latency hides under MFMA
    float e0 = ee[kbase + l15], e1 = ee[kbase + 16 + l15];

    f32x4 acc[2];
    acc[0] = (f32x4){0.f, 0.f, 0.f, 0.f};
    acc[1] = (f32x4){0.f, 0.f, 0.f, 0.f};
    __builtin_amdgcn_s_setprio(1);
    #pragma unroll
    for (int kk = 0; kk < 8; ++kk) {
      bf16x8 b0 = *reinterpret_cast<const bf16x8*>(&qbuf[(l15)      * PITCH + quad * 8 + kk * 32]);
      bf16x8 b1 = *reinterpret_cast<const bf16x8*>(&qbuf[(16 + l15) * PITCH + quad * 8 + kk * 32]);
      acc[0] = __builtin_amdgcn_mfma_f32_16x16x32_bf16(afrag[kk], b0, acc[0], 0, 0, 0);
      acc[1] = __builtin_amdgcn_mfma_f32_16x16x32_bf16(afrag[kk], b1, acc[1], 0, 0, 0);
    }
    __builtin_amdgcn_s_setprio(0);

    float en0 = sqrtf(e0), en1 = sqrtf(e1);
    #pragma unroll
    for (int r = 0; r < 4; ++r) {
      float d0 = e0 - 2.f * acc[0][r];
      float d1 = e1 - 2.f * acc[1][r];
      float w = fminf(d0, d1);
      #pragma unroll
      for (int off = 1; off < 16; off <<= 1) w = fminf(w, __shfl_xor(w, off, 64));
      float am = fminf(amin[r], w);
      amin[r] = am;
      int tok = ts * 16 + quad * 4 + r;
      float zn = znreg[r];
      // margin >= 2*eps(bf16 screen); per-half running amin keeps the bound
      if (d0 <= am + 1.5f + 0.002f * zn * en0) {
        int sl = atomicAdd(&ccnt[tok], 1);
        if (sl < MAXC) cand[tok * MAXC + sl] = (unsigned short)(kbase + l15);
      }
      if (d1 <= am + 1.5f + 0.002f * zn * en1) {
        int sl = atomicAdd(&ccnt[tok], 1);
        if (sl < MAXC) cand[tok * MAXC + sl] = (unsigned short)(kbase + 16 + l15);
      }
    }
    __syncthreads();  // all reads of qbuf done before next stage overwrites
  }

  // ---- phase 1: exact fp32 rescore (candidate loop 4-way unrolled) ----
  for (int it = 0; it < 8; ++it) {
    int tok = wv * 8 + it;
    int n = n0 + tok;
    float4 zv = *reinterpret_cast<const float4*>(z + (size_t)n * 256 + lane * 4);
    int cnt = ccnt[tok];
    float bs = 3.4e38f; int bk = 0;
    if (cnt > MAXC) {  // overflow safety net: exact scan of all K, 2-unrolled
      for (int k = 0; k < K; k += 2) {
        float4 ea = *reinterpret_cast<const float4*>(cb + (size_t)k * 256 + lane * 4);
        float4 eb = *reinterpret_cast<const float4*>(cb + (size_t)(k + 1) * 256 + lane * 4);
        float pa = zv.x * ea.x + zv.y * ea.y + zv.z * ea.z + zv.w * ea.w;
        float pb = zv.x * eb.x + zv.y * eb.y + zv.z * eb.z + zv.w * eb.w;
        #pragma unroll
        for (int off = 32; off; off >>= 1) {
          pa += __shfl_xor(pa, off, 64);
          pb += __shfl_xor(pb, off, 64);
        }
        float sa = ee[k] - 2.f * pa;
        float sb = ee[k + 1] - 2.f * pb;
        if (sa < bs) { bs = sa; bk = k; }
        if (sb < bs) { bs = sb; bk = k + 1; }
      }
    } else {
      int c = 0;
      for (; c + 4 <= cnt; c += 4) {
        int k0 = cand[tok * MAXC + c];
        int k1 = cand[tok * MAXC + c + 1];
        int k2 = cand[tok * MAXC + c + 2];
        int k3 = cand[tok * MAXC + c + 3];
        float4 e0 = *reinterpret_cast<const float4*>(cb + (size_t)k0 * 256 + lane * 4);
        float4 e1 = *reinterpret_cast<const float4*>(cb + (size_t)k1 * 256 + lane * 4);
        float4 e2 = *reinterpret_cast<const float4*>(cb + (size_t)k2 * 256 + lane * 4);
        float4 e3 = *reinterpret_cast<const float4*>(cb + (size_t)k3 * 256 + lane * 4);
        float p0 = zv.x * e0.x + zv.y * e0.y + zv.z * e0.z + zv.w * e0.w;
        float p1 = zv.x * e1.x + zv.y * e1.y + zv.z * e1.z + zv.w * e1.w;
        float p2 = zv.x * e2.x + zv.y * e2.y + zv.z * e2.z + zv.w * e2.w;
        float p3 = zv.x * e3.x + zv.y * e3.y + zv.z * e3.z + zv.w * e3.w;
        #pragma unroll
        for (int off = 32; off; off >>= 1) {   // 4 independent reduce chains
          p0 += __shfl_xor(p0, off, 64);
          p1 += __shfl_xor(p1, off, 64);
          p2 += __shfl_xor(p2, off, 64);
          p3 += __shfl_xor(p3, off, 64);
        }
        float s0 = ee[k0] - 2.f * p0;
        float s1 = ee[k1] - 2.f * p1;
        float s2 = ee[k2] - 2.f * p2;
        float s3 = ee[k3] - 2.f * p3;
        if (s0 < bs || (s0 == bs && k0 < bk)) { bs = s0; bk = k0; }
        if (s1 < bs || (s1 == bs && k1 < bk)) { bs = s1; bk = k1; }
        if (s2 < bs || (s2 == bs && k2 < bk)) { bs = s2; bk = k2; }
        if (s3 < bs || (s3 == bs && k3 < bk)) { bs = s3; bk = k3; }
      }
      for (; c < cnt; ++c) {
        int k = cand[tok * MAXC + c];
        float4 ev = *reinterpret_cast<const float4*>(cb + (size_t)k * 256 + lane * 4);
        float dp = zv.x * ev.x + zv.y * ev.y + zv.z * ev.z + zv.w * ev.w;
        #pragma unroll
        for (int off = 32; off; off >>= 1) dp += __shfl_xor(dp, off, 64);
        float s = ee[k] - 2.f * dp;   // identical on all lanes
        if (s < bs || (s == bs && k < bk)) { bs = s; bk = k; }
      }
    }
    bkbuf[tok] = (unsigned short)bk;
  }

  // ---- phase 2: outputs + loss, 2 tokens in flight ----
  float lsum = 0.f, msum = 0.f;
  for (int it = 0; it < 8; it += 2) {
    int tokA = wv * 8 + it, tokB = tokA + 1;
    int na = n0 + tokA, nb = n0 + tokB;
    int ba = bkbuf[tokA], bb = bkbuf[tokB];
    float4 za = *reinterpret_cast<const float4*>(z + (size_t)na * 256 + lane * 4);
    float4 zb = *reinterpret_cast<const float4*>(z + (size_t)nb * 256 + lane * 4);
    float4 qa = *reinterpret_cast<const float4*>(cb + (size_t)ba * 256 + lane * 4);
    float4 qb = *reinterpret_cast<const float4*>(cb + (size_t)bb * 256 + lane * 4);
    float ma = mask[na], mb = mask[nb];
    float4 oa; oa.x = qa.x * ma; oa.y = qa.y * ma; oa.z = qa.z * ma; oa.w = qa.w * ma;
    float4 ob; ob.x = qb.x * mb; ob.y = qb.y * mb; ob.z = qb.z * mb; ob.w = qb.w * mb;
    *reinterpret_cast<float4*>(out_q + (size_t)na * 256 + lane * 4) = oa;
    *reinterpret_cast<float4*>(out_q + (size_t)nb * 256 + lane * 4) = ob;
    float dxa = za.x - qa.x, dya = za.y - qa.y, dza = za.z - qa.z, dwa = za.w - qa.w;
    float dxb = zb.x - qb.x, dyb = zb.y - qb.y, dzb = zb.z - qb.z, dwb = zb.w - qb.w;
    lsum = fmaf(ma, dxa * dxa + dya * dya + dza * dza + dwa * dwa, lsum);
    lsum = fmaf(mb, dxb * dxb + dyb * dyb + dzb * dzb + dwb * dwb, lsum);
    if (lane == 0) {
      msum += ma + mb;
      out_idx_f[na] = (ma > 0.f) ? (float)ba : 0.f;
      out_idx_f[nb] = (mb > 0.f) ? (float)bb : 0.f;
    }
  }
  #pragma unroll
  for (int off = 32; off; off >>= 1) lsum += __shfl_down(lsum, off, 64);
  if (lane == 0) { red[wv] = lsum; red[4 + wv] = msum; }
  __syncthreads();
  if (t == 0) {
    atomicAdd(&acc2[0], red[0] + red[1] + red[2] + red[3]);
    atomicAdd(&acc2[1], red[4] + red[5] + red[6] + red[7]);
    __threadfence();
    int prev = atomicAdd(done_ctr, 1);
    last = (prev == nblocks - 1);
  }
  __syncthreads();
  if (last && t == 0) {
    float s  = atomicAdd(&acc2[0], 0.0f);
    float nv = atomicAdd(&acc2[1], 0.0f);
    out_loss[0] = (nv > 0.f) ? (0.25f * s / (nv * 256.0f)) : 0.0f;
  }
}

// ---------------------------------------------------------------------------
extern "C" void kernel_launch(void* const* d_in, const int* in_sizes, int n_in,
                              void* d_out, int out_size, void* d_ws, size_t ws_size,
                              hipStream_t stream) {
  const float* z    = (const float*)d_in[0];  // (N, 256)
  const float* mask = (const float*)d_in[1];  // (N,)
  const float* cb   = (const float*)d_in[2];  // (K, 256)
  const int N = in_sizes[1];                  // 32768
  const int D = 256;
  const int K = in_sizes[2] / D;              // 1024

  float* wsf  = (float*)d_ws;
  float* acc2 = wsf;                          // 2 floats
  int*   dctr = (int*)(wsf + 2);              // 1 int
  float* ee   = wsf + 8;                      // K floats
  unsigned short* cb_bf = (unsigned short*)(ee + K);  // K*256 bf16

  float* out_q     = (float*)d_out;           // N*D
  float* out_loss  = out_q + (size_t)N * D;   // 1
  float* out_idx_f = out_loss + 1;            // N

  vq_prep<<<(K + 3) / 4, 256, 0, stream>>>(cb, cb_bf, ee, acc2, dctr, K);
  vq_main<<<N / TOK, 256, 0, stream>>>(z, cb, cb_bf, ee, mask, out_q,
                                       out_idx_f, out_loss, acc2, dctr, N / TOK, K);
}

// Round 7
// 233.055 us; speedup vs baseline: 1.3539x; 1.3539x over previous
//
#include <hip/hip_runtime.h>
#include <cstdint>

typedef short bf16x8 __attribute__((ext_vector_type(8)));
typedef float f32x4  __attribute__((ext_vector_type(4)));

#define TOK    32         // tokens per block (grid 1024)
#define PITCH  264        // ushorts/row for z-stage (256 + 8 pad)
#define MAXC   32

__device__ __forceinline__ unsigned short f2bf(float f) {
  unsigned u = __float_as_uint(f);
  return (unsigned short)((u + 0x7FFFu + ((u >> 16) & 1u)) >> 16);
}
__device__ __forceinline__ uint4 pack8(float4 a, float4 b) {
  uint4 u;
  u.x = (unsigned)f2bf(a.x) | ((unsigned)f2bf(a.y) << 16);
  u.y = (unsigned)f2bf(a.z) | ((unsigned)f2bf(a.w) << 16);
  u.z = (unsigned)f2bf(b.x) | ((unsigned)f2bf(b.y) << 16);
  u.w = (unsigned)f2bf(b.z) | ((unsigned)f2bf(b.w) << 16);
  return u;
}

// ---------------------------------------------------------------------------
// Prep: ee = ||cb_k||^2; cb_fr = bf16 codebook in FRAGMENT-MAJOR layout so the
// main kernel's per-wave B-fragment loads are lane-contiguous (1 KB coalesced
// per instruction). For code k (block cbblk=k>>5, r=k&31, b01=r>>4, l15=r&15)
// and dim d (kk=d>>5, quad=(d&31)>>3, e=d&7):
//   cb_fr[ (cbblk*16 + kk*2 + b01)*512 + (quad*16 + l15)*8 + e ]
// Main-loop load: fb = cb_fr + cbblk*8192 + kk*1024 + b01*512 + lane*8.
// ---------------------------------------------------------------------------
__global__ __launch_bounds__(256) void vq_prep(const float* __restrict__ cb,
                                               unsigned short* __restrict__ cb_fr,
                                               float* __restrict__ ee,
                                               float* __restrict__ acc2,
                                               int* __restrict__ done_ctr, int K) {
  if (blockIdx.x == 0 && threadIdx.x == 0) {
    acc2[0] = 0.f; acc2[1] = 0.f; *done_ctr = 0;
  }
  int wave = threadIdx.x >> 6, lane = threadIdx.x & 63;
  int k = blockIdx.x * 4 + wave;
  if (k >= K) return;
  float4 v = *reinterpret_cast<const float4*>(cb + (size_t)k * 256 + lane * 4);
  float s = v.x * v.x + v.y * v.y + v.z * v.z + v.w * v.w;
  #pragma unroll
  for (int off = 32; off; off >>= 1) s += __shfl_down(s, off, 64);
  ushort4 b;
  b.x = f2bf(v.x); b.y = f2bf(v.y); b.z = f2bf(v.z); b.w = f2bf(v.w);
  int d = lane * 4;
  int cbblk = k >> 5, r = k & 31, b01 = r >> 4, l15r = r & 15;
  int kk = d >> 5, quad = (d & 31) >> 3, e = d & 7;
  size_t dst = ((size_t)cbblk * 16 + kk * 2 + b01) * 512 + (quad * 16 + l15r) * 8 + e;
  *reinterpret_cast<ushort4*>(cb_fr + dst) = b;
  if (lane == 0) ee[k] = s;
}

// ---------------------------------------------------------------------------
// Main: 256 thr (4 waves), TOK=32, grid 1024, __launch_bounds__(256,2).
// BARRIER-FREE main loop. Evidence R0-R6: every barrier-synced variant
// (serial/reg-prefetch/async-DMA staging, 2 or 4 blocks/CU) hits the same
// ~106+ us all-pipes-idle floor -> the block-wide rendezvous per chunk IS
// the bottleneck. Here each wave (ts=wv&1, kh=wv>>1) owns 16 tokens x a
// K-half and streams B-fragments DIRECTLY from L2 (cb_fr fragment-major,
// coalesced bf16x8 loads), no LDS staging, no vmcnt drains, no syncthreads
// until the single pre-epilogue barrier. LDS = z-stage + cand arrays only
// (~20 KB). Numerics byte-identical to passing R6 config: per-half running
// amin, margin 1.5 + 0.002*zn*en, ushort cand MAXC=32, exact fp32 rescore
// (R5 ILP form), exact-scan overflow fallback.
// DO NOT: 512-thread blocks (VGPR crush + spill); __launch_bounds__ 2nd arg
// >2 (R6: crushed to 52 VGPR, killed epilogue ILP); big register prefetch
// arrays (R3 spill); MAXC<32 or looser margin (R2: 4x straggler blowup).
// ---------------------------------------------------------------------------
__global__ __launch_bounds__(256, 2) void vq_main(
    const float* __restrict__ z, const float* __restrict__ cb,
    const unsigned short* __restrict__ cb_fr, const float* __restrict__ ee,
    const float* __restrict__ mask,
    float* __restrict__ out_q, float* __restrict__ out_idx_f,
    float* __restrict__ out_loss, float* __restrict__ acc2,
    int* __restrict__ done_ctr, int nblocks, int K) {
  __shared__ __align__(16) unsigned short buf[TOK * PITCH];  // 16.9 KB z-stage
  __shared__ float znorm[TOK];
  __shared__ int   ccnt[TOK];
  __shared__ unsigned short cand[TOK * MAXC];                // 2 KB
  __shared__ unsigned short bkbuf[TOK];
  __shared__ float red[8];
  __shared__ bool  last;

  const int t = threadIdx.x;
  const int n0 = blockIdx.x * TOK;
  const int wv = t >> 6, lane = t & 63;
  const int ts = wv & 1, kh = wv >> 1;
  const int quad = lane >> 4, l15 = lane & 15;
  const int q16 = t & 15;

  if (t < TOK) ccnt[t] = 0;

  // ---- stage z -> bf16 into buf rows 0..31; ||z|| ----
  #pragma unroll
  for (int pass = 0; pass < 2; ++pass) {
    int row = pass * 16 + (t >> 4);
    const float* zr = z + (size_t)(n0 + row) * 256;
    float ssq = 0.f;
    #pragma unroll
    for (int j = 0; j < 2; ++j) {
      float4 a = *reinterpret_cast<const float4*>(zr + q16 * 8 + j * 128);
      float4 b = *reinterpret_cast<const float4*>(zr + q16 * 8 + j * 128 + 4);
      ssq += a.x*a.x + a.y*a.y + a.z*a.z + a.w*a.w
           + b.x*b.x + b.y*b.y + b.z*b.z + b.w*b.w;
      *reinterpret_cast<uint4*>(&buf[row * PITCH + q16 * 8 + j * 128]) = pack8(a, b);
    }
    #pragma unroll
    for (int off = 1; off < 16; off <<= 1) ssq += __shfl_xor(ssq, off, 64);
    if (q16 == 0) znorm[row] = sqrtf(ssq);
  }
  __syncthreads();  // S1: z staged (buf is never overwritten after this)

  // ---- A fragments into registers: wave owns token rows ts*16 + l15 ----
  bf16x8 afrag[8];
  float  znreg[4];
  {
    const unsigned short* za = &buf[(ts * 16 + l15) * PITCH + quad * 8];
    #pragma unroll
    for (int kk = 0; kk < 8; ++kk)
      afrag[kk] = *reinterpret_cast<const bf16x8*>(za + kk * 32);
    #pragma unroll
    for (int r = 0; r < 4; ++r)
      znreg[r] = znorm[ts * 16 + quad * 4 + r];
  }

  float amin[4] = {3.4e38f, 3.4e38f, 3.4e38f, 3.4e38f};
  // wave-private fragment stream base: K-half kh = 16 code-blocks of 32
  const unsigned short* fbase = cb_fr + (size_t)kh * 16 * 8192 + lane * 8;

  // ---- chunk loop: 16 chunks x 32 codes, NO BARRIERS, stream from L2 ----
  #pragma unroll 1
  for (int lc = 0; lc < 16; ++lc) {
    const int kbase = kh * 512 + lc * 32;
    const unsigned short* fb = fbase + (size_t)lc * 8192;
    float e0 = ee[kbase + l15], e1 = ee[kbase + 16 + l15];

    f32x4 acc0 = (f32x4){0.f, 0.f, 0.f, 0.f};
    f32x4 acc1 = (f32x4){0.f, 0.f, 0.f, 0.f};
    __builtin_amdgcn_s_setprio(1);
    #pragma unroll
    for (int kk = 0; kk < 8; ++kk) {
      bf16x8 b0 = *reinterpret_cast<const bf16x8*>(fb + kk * 1024);
      bf16x8 b1 = *reinterpret_cast<const bf16x8*>(fb + kk * 1024 + 512);
      acc0 = __builtin_amdgcn_mfma_f32_16x16x32_bf16(afrag[kk], b0, acc0, 0, 0, 0);
      acc1 = __builtin_amdgcn_mfma_f32_16x16x32_bf16(afrag[kk], b1, acc1, 0, 0, 0);
    }
    __builtin_amdgcn_s_setprio(0);

    float en0 = sqrtf(e0), en1 = sqrtf(e1);
    #pragma unroll
    for (int r = 0; r < 4; ++r) {
      float d0 = e0 - 2.f * acc0[r];
      float d1 = e1 - 2.f * acc1[r];
      float w = fminf(d0, d1);
      #pragma unroll
      for (int off = 1; off < 16; off <<= 1) w = fminf(w, __shfl_xor(w, off, 64));
      float am = fminf(amin[r], w);
      amin[r] = am;
      int tok = ts * 16 + quad * 4 + r;
      float zn = znreg[r];
      // margin >= 2*eps(bf16 screen); per-half running amin keeps the bound
      if (d0 <= am + 1.5f + 0.002f * zn * en0) {
        int sl = atomicAdd(&ccnt[tok], 1);
        if (sl < MAXC) cand[tok * MAXC + sl] = (unsigned short)(kbase + l15);
      }
      if (d1 <= am + 1.5f + 0.002f * zn * en1) {
        int sl = atomicAdd(&ccnt[tok], 1);
        if (sl < MAXC) cand[tok * MAXC + sl] = (unsigned short)(kbase + 16 + l15);
      }
    }
  }
  __syncthreads();  // single rendezvous: cand/ccnt visible to all waves

  // ---- phase 1: exact fp32 rescore (candidate loop 4-way unrolled) ----
  for (int it = 0; it < 8; ++it) {
    int tok = wv * 8 + it;
    int n = n0 + tok;
    float4 zv = *reinterpret_cast<const float4*>(z + (size_t)n * 256 + lane * 4);
    int cnt = ccnt[tok];
    float bs = 3.4e38f; int bk = 0;
    if (cnt > MAXC) {  // overflow safety net: exact scan of all K, 2-unrolled
      for (int k = 0; k < K; k += 2) {
        float4 ea = *reinterpret_cast<const float4*>(cb + (size_t)k * 256 + lane * 4);
        float4 eb = *reinterpret_cast<const float4*>(cb + (size_t)(k + 1) * 256 + lane * 4);
        float pa = zv.x * ea.x + zv.y * ea.y + zv.z * ea.z + zv.w * ea.w;
        float pb = zv.x * eb.x + zv.y * eb.y + zv.z * eb.z + zv.w * eb.w;
        #pragma unroll
        for (int off = 32; off; off >>= 1) {
          pa += __shfl_xor(pa, off, 64);
          pb += __shfl_xor(pb, off, 64);
        }
        float sa = ee[k] - 2.f * pa;
        float sb = ee[k + 1] - 2.f * pb;
        if (sa < bs) { bs = sa; bk = k; }
        if (sb < bs) { bs = sb; bk = k + 1; }
      }
    } else {
      int c = 0;
      for (; c + 4 <= cnt; c += 4) {
        int k0 = cand[tok * MAXC + c];
        int k1 = cand[tok * MAXC + c + 1];
        int k2 = cand[tok * MAXC + c + 2];
        int k3 = cand[tok * MAXC + c + 3];
        float4 e0 = *reinterpret_cast<const float4*>(cb + (size_t)k0 * 256 + lane * 4);
        float4 e1 = *reinterpret_cast<const float4*>(cb + (size_t)k1 * 256 + lane * 4);
        float4 e2 = *reinterpret_cast<const float4*>(cb + (size_t)k2 * 256 + lane * 4);
        float4 e3 = *reinterpret_cast<const float4*>(cb + (size_t)k3 * 256 + lane * 4);
        float p0 = zv.x * e0.x + zv.y * e0.y + zv.z * e0.z + zv.w * e0.w;
        float p1 = zv.x * e1.x + zv.y * e1.y + zv.z * e1.z + zv.w * e1.w;
        float p2 = zv.x * e2.x + zv.y * e2.y + zv.z * e2.z + zv.w * e2.w;
        float p3 = zv.x * e3.x + zv.y * e3.y + zv.z * e3.z + zv.w * e3.w;
        #pragma unroll
        for (int off = 32; off; off >>= 1) {   // 4 independent reduce chains
          p0 += __shfl_xor(p0, off, 64);
          p1 += __shfl_xor(p1, off, 64);
          p2 += __shfl_xor(p2, off, 64);
          p3 += __shfl_xor(p3, off, 64);
        }
        float s0 = ee[k0] - 2.f * p0;
        float s1 = ee[k1] - 2.f * p1;
        float s2 = ee[k2] - 2.f * p2;
        float s3 = ee[k3] - 2.f * p3;
        if (s0 < bs || (s0 == bs && k0 < bk)) { bs = s0; bk = k0; }
        if (s1 < bs || (s1 == bs && k1 < bk)) { bs = s1; bk = k1; }
        if (s2 < bs || (s2 == bs && k2 < bk)) { bs = s2; bk = k2; }
        if (s3 < bs || (s3 == bs && k3 < bk)) { bs = s3; bk = k3; }
      }
      for (; c < cnt; ++c) {
        int k = cand[tok * MAXC + c];
        float4 ev = *reinterpret_cast<const float4*>(cb + (size_t)k * 256 + lane * 4);
        float dp = zv.x * ev.x + zv.y * ev.y + zv.z * ev.z + zv.w * ev.w;
        #pragma unroll
        for (int off = 32; off; off >>= 1) dp += __shfl_xor(dp, off, 64);
        float s = ee[k] - 2.f * dp;   // identical on all lanes
        if (s < bs || (s == bs && k < bk)) { bs = s; bk = k; }
      }
    }
    bkbuf[tok] = (unsigned short)bk;
  }

  // ---- phase 2: outputs + loss, 2 tokens in flight ----
  float lsum = 0.f, msum = 0.f;
  for (int it = 0; it < 8; it += 2) {
    int tokA = wv * 8 + it, tokB = tokA + 1;
    int na = n0 + tokA, nb = n0 + tokB;
    int ba = bkbuf[tokA], bb = bkbuf[tokB];
    float4 za = *reinterpret_cast<const float4*>(z + (size_t)na * 256 + lane * 4);
    float4 zb = *reinterpret_cast<const float4*>(z + (size_t)nb * 256 + lane * 4);
    float4 qa = *reinterpret_cast<const float4*>(cb + (size_t)ba * 256 + lane * 4);
    float4 qb = *reinterpret_cast<const float4*>(cb + (size_t)bb * 256 + lane * 4);
    float ma = mask[na], mb = mask[nb];
    float4 oa; oa.x = qa.x * ma; oa.y = qa.y * ma; oa.z = qa.z * ma; oa.w = qa.w * ma;
    float4 ob; ob.x = qb.x * mb; ob.y = qb.y * mb; ob.z = qb.z * mb; ob.w = qb.w * mb;
    *reinterpret_cast<float4*>(out_q + (size_t)na * 256 + lane * 4) = oa;
    *reinterpret_cast<float4*>(out_q + (size_t)nb * 256 + lane * 4) = ob;
    float dxa = za.x - qa.x, dya = za.y - qa.y, dza = za.z - qa.z, dwa = za.w - qa.w;
    float dxb = zb.x - qb.x, dyb = zb.y - qb.y, dzb = zb.z - qb.z, dwb = zb.w - qb.w;
    lsum = fmaf(ma, dxa * dxa + dya * dya + dza * dza + dwa * dwa, lsum);
    lsum = fmaf(mb, dxb * dxb + dyb * dyb + dzb * dzb + dwb * dwb, lsum);
    if (lane == 0) {
      msum += ma + mb;
      out_idx_f[na] = (ma > 0.f) ? (float)ba : 0.f;
      out_idx_f[nb] = (mb > 0.f) ? (float)bb : 0.f;
    }
  }
  #pragma unroll
  for (int off = 32; off; off >>= 1) lsum += __shfl_down(lsum, off, 64);
  if (lane == 0) { red[wv] = lsum; red[4 + wv] = msum; }
  __syncthreads();
  if (t == 0) {
    atomicAdd(&acc2[0], red[0] + red[1] + red[2] + red[3]);
    atomicAdd(&acc2[1], red[4] + red[5] + red[6] + red[7]);
    __threadfence();
    int prev = atomicAdd(done_ctr, 1);
    last = (prev == nblocks - 1);
  }
  __syncthreads();
  if (last && t == 0) {
    float s  = atomicAdd(&acc2[0], 0.0f);
    float nv = atomicAdd(&acc2[1], 0.0f);
    out_loss[0] = (nv > 0.f) ? (0.25f * s / (nv * 256.0f)) : 0.0f;
  }
}

// ---------------------------------------------------------------------------
extern "C" void kernel_launch(void* const* d_in, const int* in_sizes, int n_in,
                              void* d_out, int out_size, void* d_ws, size_t ws_size,
                              hipStream_t stream) {
  const float* z    = (const float*)d_in[0];  // (N, 256)
  const float* mask = (const float*)d_in[1];  // (N,)
  const float* cb   = (const float*)d_in[2];  // (K, 256)
  const int N = in_sizes[1];                  // 32768
  const int D = 256;
  const int K = in_sizes[2] / D;              // 1024

  float* wsf  = (float*)d_ws;
  float* acc2 = wsf;                          // 2 floats
  int*   dctr = (int*)(wsf + 2);              // 1 int
  float* ee   = wsf + 8;                      // K floats
  unsigned short* cb_fr = (unsigned short*)(ee + K);  // K*256 bf16, fragment-major

  float* out_q     = (float*)d_out;           // N*D
  float* out_loss  = out_q + (size_t)N * D;   // 1
  float* out_idx_f = out_loss + 1;            // N

  vq_prep<<<(K + 3) / 4, 256, 0, stream>>>(cb, cb_fr, ee, acc2, dctr, K);
  vq_main<<<N / TOK, 256, 0, stream>>>(z, cb, cb_fr, ee, mask, out_q,
                                       out_idx_f, out_loss, acc2, dctr, N / TOK, K);
}

// Round 8
// 178.397 us; speedup vs baseline: 1.7687x; 1.3064x over previous
//
#include <hip/hip_runtime.h>
#include <cstdint>

typedef short bf16x8 __attribute__((ext_vector_type(8)));
typedef float f32x4  __attribute__((ext_vector_type(4)));

#define TOK    64         // tokens per block
#define CH     64         // codes per chunk
#define NCH    16         // chunks (K=1024)
#define BUFW   16384      // ushorts per chunk buffer (64 rows x 256)
#define MAXC   32

__device__ __forceinline__ unsigned short f2bf(float f) {
  unsigned u = __float_as_uint(f);
  return (unsigned short)((u + 0x7FFFu + ((u >> 16) & 1u)) >> 16);
}
__device__ __forceinline__ uint4 pack8(float4 a, float4 b) {
  uint4 u;
  u.x = (unsigned)f2bf(a.x) | ((unsigned)f2bf(a.y) << 16);
  u.y = (unsigned)f2bf(a.z) | ((unsigned)f2bf(a.w) << 16);
  u.z = (unsigned)f2bf(b.x) | ((unsigned)f2bf(b.y) << 16);
  u.w = (unsigned)f2bf(b.z) | ((unsigned)f2bf(b.w) << 16);
  return u;
}
// async global->LDS DMA, 16 B per lane. LDS dest must be wave-uniform base
// (HW adds lane*16); global src is per-lane. Zero VGPR staging cost.
__device__ __forceinline__ void gload16(const unsigned short* g, unsigned short* l) {
  __builtin_amdgcn_global_load_lds(
      (const __attribute__((address_space(1))) unsigned int*)(const void*)g,
      (__attribute__((address_space(3))) unsigned int*)(void*)l, 16, 0, 0);
}

// ---------------------------------------------------------------------------
// Prep: cb_bf = bf16(cb), ee = ||cb_k||^2. Block 0 zeroes global accumulators.
// ---------------------------------------------------------------------------
__global__ __launch_bounds__(256) void vq_prep(const float* __restrict__ cb,
                                               unsigned short* __restrict__ cb_bf,
                                               float* __restrict__ ee,
                                               float* __restrict__ acc2,
                                               int* __restrict__ done_ctr, int K) {
  if (blockIdx.x == 0 && threadIdx.x == 0) {
    acc2[0] = 0.f; acc2[1] = 0.f; *done_ctr = 0;
  }
  int wave = threadIdx.x >> 6, lane = threadIdx.x & 63;
  int k = blockIdx.x * 4 + wave;
  if (k >= K) return;
  float4 v = *reinterpret_cast<const float4*>(cb + (size_t)k * 256 + lane * 4);
  float s = v.x * v.x + v.y * v.y + v.z * v.z + v.w * v.w;
  #pragma unroll
  for (int off = 32; off; off >>= 1) s += __shfl_down(s, off, 64);
  ushort4 b;
  b.x = f2bf(v.x); b.y = f2bf(v.y); b.z = f2bf(v.z); b.w = f2bf(v.w);
  *reinterpret_cast<ushort4*>(cb_bf + (size_t)k * 256 + lane * 4) = b;
  if (lane == 0) ee[k] = s;
}

// ---------------------------------------------------------------------------
// Main: 256 thr (4 waves), TOK=64, grid 512 -> 2 blocks/CU (LDS ~74.5 KB).
// R5 chassis (async dbuf global_load_lds staging, XOR granule swizzle, ILP
// epilogue = 106 us) with ONE change: the screen's 4x 4-step __shfl_xor
// min-reduce chains (ds_bpermute latency, the largest non-MFMA block in the
// hot loop; R7 showed conflicts/DS traffic live here) are replaced by an
// LDS packed-float atomicMin gate:
//   atomicMin(&umin[tok], clamp(min(d0..d3))); gate = umin[tok];
// Same-wave DS ops are in-order -> the read sees all 16 lanes' atomics, so
// the gate equals the shuffle result EXACTLY, plus cross-wave sharing (other
// K-half). Gate <= R5 gate => candidate set is a SUBSET (no overflow-
// regression risk, R2 lesson). Winner containment: true argmin k* satisfies
// dhat_k* <= gate + 2*eps for any gate built from published dhat (clamping
// only raises the gate); margin 1.5 + 0.002*zn*en >= 2*eps as in R0-R5.
// DO NOT: 512-thread blocks (VGPR crush + spill); __launch_bounds__ 2nd arg
// >2 (R6: crushed to 52 VGPR); register prefetch arrays (R3 spill); MAXC<32
// or looser margin (R2: 4x straggler blowup); barrier-free L2 streaming
// (R7: compiler won't pipeline global->MFMA, 165 us).
// ---------------------------------------------------------------------------
__global__ __launch_bounds__(256, 2) void vq_main(
    const float* __restrict__ z, const float* __restrict__ cb,
    const unsigned short* __restrict__ cb_bf, const float* __restrict__ ee,
    const float* __restrict__ mask,
    float* __restrict__ out_q, float* __restrict__ out_idx_f,
    float* __restrict__ out_loss, float* __restrict__ acc2,
    int* __restrict__ done_ctr, int nblocks, int K) {
  __shared__ __align__(16) unsigned short sbuf[2 * BUFW];    // 64 KB: dbuf chunks; buf0 doubles as z-stage
  __shared__ float ee_lds[1024];                             // 4 KB
  __shared__ float znorm[TOK];
  __shared__ int   ccnt[TOK];
  __shared__ unsigned umin[TOK];                             // packed float gate (nonneg -> uint order)
  __shared__ unsigned short cand[TOK * MAXC];                // 4 KB
  __shared__ unsigned short bkbuf[TOK];                      // winner index per token
  __shared__ float red[8];
  __shared__ bool  last;

  const int t = threadIdx.x;
  const int n0 = blockIdx.x * TOK;
  const int wv = t >> 6, lane = t & 63;
  const int quad = lane >> 4, l15 = lane & 15;
  const int q16 = t & 15;

  // ---- code norms into LDS ----
  ee_lds[t]       = ee[t];
  ee_lds[t + 256] = ee[t + 256];
  ee_lds[t + 512] = ee[t + 512];
  ee_lds[t + 768] = ee[t + 768];
  if (t < TOK) { ccnt[t] = 0; umin[t] = 0x7F7FFFFFu; }

  // ---- stage z -> bf16 into buf0 rows 0..63 (swizzled); ||z|| ----
  #pragma unroll
  for (int pass = 0; pass < 4; ++pass) {
    int row = pass * 16 + (t >> 4);
    const float* zr = z + (size_t)(n0 + row) * 256;
    float ssq = 0.f;
    #pragma unroll
    for (int j = 0; j < 2; ++j) {
      float4 a = *reinterpret_cast<const float4*>(zr + q16 * 16 + j * 8);
      float4 b = *reinterpret_cast<const float4*>(zr + q16 * 16 + j * 8 + 4);
      ssq += a.x*a.x + a.y*a.y + a.z*a.z + a.w*a.w
           + b.x*b.x + b.y*b.y + b.z*b.z + b.w*b.w;
      int g = q16 * 2 + j;                       // logical granule 0..31
      *reinterpret_cast<uint4*>(&sbuf[row * 256 + ((g ^ (row & 7)) * 8)]) = pack8(a, b);
    }
    #pragma unroll
    for (int off = 1; off < 16; off <<= 1) ssq += __shfl_xor(ssq, off, 64);
    if (q16 == 0) znorm[row] = sqrtf(ssq);
  }
  __syncthreads();  // S1: z staged

  // ---- A fragments into registers: wave wv owns token rows wv*16 + l15 ----
  bf16x8 afrag[8];
  float  znreg[4];
  {
    int row = wv * 16 + l15;
    #pragma unroll
    for (int kk = 0; kk < 8; ++kk) {
      int g = (quad + kk * 4) ^ (row & 7);
      afrag[kk] = *reinterpret_cast<const bf16x8*>(&sbuf[row * 256 + g * 8]);
    }
    #pragma unroll
    for (int r = 0; r < 4; ++r)
      znreg[r] = znorm[wv * 16 + quad * 4 + r];
  }
  __syncthreads();  // S2: all A-loads done before chunk 0 overwrites buf0

  // ---- prologue: issue chunk 0 -> buf0 (async DMA), wait, publish ----
  {
    #pragma unroll
    for (int i = 0; i < 8; ++i) {
      int f = (wv * 8 + i) * 64 + lane;          // granule 0..2047
      int row = f >> 5, slot = f & 31;
      gload16(cb_bf + (size_t)row * 256 + ((slot ^ (row & 7)) * 8),
              &sbuf[(size_t)(wv * 512 + i * 64) * 8]);
    }
  }
  asm volatile("s_waitcnt vmcnt(0)" ::: "memory");
  __syncthreads();  // S3: chunk 0 visible

  // ---- chunk loop: 16 chunks x 64 codes, double-buffered async staging ----
  for (int lc = 0; lc < NCH; ++lc) {
    const int kbase = lc * CH;
    unsigned short* cur = &sbuf[(lc & 1) * BUFW];
    unsigned short* nxt = &sbuf[((lc + 1) & 1) * BUFW];
    if (lc < NCH - 1) {  // issue next chunk's DMA before compute
      const unsigned short* base = cb_bf + (size_t)(kbase + CH) * 256;
      #pragma unroll
      for (int i = 0; i < 8; ++i) {
        int f = (wv * 8 + i) * 64 + lane;
        int row = f >> 5, slot = f & 31;
        gload16(base + (size_t)row * 256 + ((slot ^ (row & 7)) * 8),
                nxt + (size_t)(wv * 512 + i * 64) * 8);
      }
    }

    f32x4 acc[4];
    #pragma unroll
    for (int ct = 0; ct < 4; ++ct) acc[ct] = (f32x4){0.f, 0.f, 0.f, 0.f};
    __builtin_amdgcn_s_setprio(1);
    #pragma unroll
    for (int kk = 0; kk < 8; ++kk) {
      int gx = quad + kk * 4;
      bf16x8 b0 = *reinterpret_cast<const bf16x8*>(&cur[(l15)      * 256 + ((gx ^ ( l15       & 7)) * 8)]);
      bf16x8 b1 = *reinterpret_cast<const bf16x8*>(&cur[(16 + l15) * 256 + ((gx ^ ((16 + l15) & 7)) * 8)]);
      bf16x8 b2 = *reinterpret_cast<const bf16x8*>(&cur[(32 + l15) * 256 + ((gx ^ ((32 + l15) & 7)) * 8)]);
      bf16x8 b3 = *reinterpret_cast<const bf16x8*>(&cur[(48 + l15) * 256 + ((gx ^ ((48 + l15) & 7)) * 8)]);
      acc[0] = __builtin_amdgcn_mfma_f32_16x16x32_bf16(afrag[kk], b0, acc[0], 0, 0, 0);
      acc[1] = __builtin_amdgcn_mfma_f32_16x16x32_bf16(afrag[kk], b1, acc[1], 0, 0, 0);
      acc[2] = __builtin_amdgcn_mfma_f32_16x16x32_bf16(afrag[kk], b2, acc[2], 0, 0, 0);
      acc[3] = __builtin_amdgcn_mfma_f32_16x16x32_bf16(afrag[kk], b3, acc[3], 0, 0, 0);
    }
    __builtin_amdgcn_s_setprio(0);

    float e0 = ee_lds[kbase + l15],      e1 = ee_lds[kbase + 16 + l15];
    float e2 = ee_lds[kbase + 32 + l15], e3 = ee_lds[kbase + 48 + l15];
    float en0 = sqrtf(e0), en1 = sqrtf(e1), en2 = sqrtf(e2), en3 = sqrtf(e3);
    #pragma unroll
    for (int r = 0; r < 4; ++r) {
      float d0 = e0 - 2.f * acc[0][r];
      float d1 = e1 - 2.f * acc[1][r];
      float d2 = e2 - 2.f * acc[2][r];
      float d3 = e3 - 2.f * acc[3][r];
      int tok = wv * 16 + quad * 4 + r;
      // publish this lane's chunk-min, then read the gate back: same-wave DS
      // ops are in-order, so the gate includes all 16 lanes of this r-group
      // (== the old shuffle-reduce) plus anything other waves published.
      float dm = fmaxf(fminf(fminf(d0, d1), fminf(d2, d3)), 0.f);
      atomicMin(&umin[tok], __float_as_uint(dm));
      float am = __uint_as_float(umin[tok]);
      float zn = znreg[r];
      // margin >= 2*eps(bf16 screen); published-gate keeps the bound
      if (d0 <= am + 1.5f + 0.002f * zn * en0) {
        int sl = atomicAdd(&ccnt[tok], 1);
        if (sl < MAXC) cand[tok * MAXC + sl] = (unsigned short)(kbase + l15);
      }
      if (d1 <= am + 1.5f + 0.002f * zn * en1) {
        int sl = atomicAdd(&ccnt[tok], 1);
        if (sl < MAXC) cand[tok * MAXC + sl] = (unsigned short)(kbase + 16 + l15);
      }
      if (d2 <= am + 1.5f + 0.002f * zn * en2) {
        int sl = atomicAdd(&ccnt[tok], 1);
        if (sl < MAXC) cand[tok * MAXC + sl] = (unsigned short)(kbase + 32 + l15);
      }
      if (d3 <= am + 1.5f + 0.002f * zn * en3) {
        int sl = atomicAdd(&ccnt[tok], 1);
        if (sl < MAXC) cand[tok * MAXC + sl] = (unsigned short)(kbase + 48 + l15);
      }
    }
    asm volatile("s_waitcnt vmcnt(0)" ::: "memory");  // next-chunk DMA landed
    __syncthreads();                                  // visible to all waves
  }

  // ---- phase 1: exact fp32 rescore (candidate loop 4-way unrolled) ----
  for (int it = 0; it < 16; ++it) {
    int tok = wv * 16 + it;
    int n = n0 + tok;
    float4 zv = *reinterpret_cast<const float4*>(z + (size_t)n * 256 + lane * 4);
    int cnt = ccnt[tok];
    float bs = 3.4e38f; int bk = 0;
    if (cnt > MAXC) {  // overflow safety net: exact scan of all K, 2-unrolled
      for (int k = 0; k < K; k += 2) {
        float4 ea = *reinterpret_cast<const float4*>(cb + (size_t)k * 256 + lane * 4);
        float4 eb = *reinterpret_cast<const float4*>(cb + (size_t)(k + 1) * 256 + lane * 4);
        float pa = zv.x * ea.x + zv.y * ea.y + zv.z * ea.z + zv.w * ea.w;
        float pb = zv.x * eb.x + zv.y * eb.y + zv.z * eb.z + zv.w * eb.w;
        #pragma unroll
        for (int off = 32; off; off >>= 1) {
          pa += __shfl_xor(pa, off, 64);
          pb += __shfl_xor(pb, off, 64);
        }
        float sa = ee_lds[k] - 2.f * pa;
        float sb = ee_lds[k + 1] - 2.f * pb;
        if (sa < bs) { bs = sa; bk = k; }
        if (sb < bs) { bs = sb; bk = k + 1; }
      }
    } else {
      int c = 0;
      for (; c + 4 <= cnt; c += 4) {
        int k0 = cand[tok * MAXC + c];
        int k1 = cand[tok * MAXC + c + 1];
        int k2 = cand[tok * MAXC + c + 2];
        int k3 = cand[tok * MAXC + c + 3];
        float4 e0 = *reinterpret_cast<const float4*>(cb + (size_t)k0 * 256 + lane * 4);
        float4 e1 = *reinterpret_cast<const float4*>(cb + (size_t)k1 * 256 + lane * 4);
        float4 e2 = *reinterpret_cast<const float4*>(cb + (size_t)k2 * 256 + lane * 4);
        float4 e3 = *reinterpret_cast<const float4*>(cb + (size_t)k3 * 256 + lane * 4);
        float p0 = zv.x * e0.x + zv.y * e0.y + zv.z * e0.z + zv.w * e0.w;
        float p1 = zv.x * e1.x + zv.y * e1.y + zv.z * e1.z + zv.w * e1.w;
        float p2 = zv.x * e2.x + zv.y * e2.y + zv.z * e2.z + zv.w * e2.w;
        float p3 = zv.x * e3.x + zv.y * e3.y + zv.z * e3.z + zv.w * e3.w;
        #pragma unroll
        for (int off = 32; off; off >>= 1) {   // 4 independent reduce chains
          p0 += __shfl_xor(p0, off, 64);
          p1 += __shfl_xor(p1, off, 64);
          p2 += __shfl_xor(p2, off, 64);
          p3 += __shfl_xor(p3, off, 64);
        }
        float s0 = ee_lds[k0] - 2.f * p0;
        float s1 = ee_lds[k1] - 2.f * p1;
        float s2 = ee_lds[k2] - 2.f * p2;
        float s3 = ee_lds[k3] - 2.f * p3;
        if (s0 < bs || (s0 == bs && k0 < bk)) { bs = s0; bk = k0; }
        if (s1 < bs || (s1 == bs && k1 < bk)) { bs = s1; bk = k1; }
        if (s2 < bs || (s2 == bs && k2 < bk)) { bs = s2; bk = k2; }
        if (s3 < bs || (s3 == bs && k3 < bk)) { bs = s3; bk = k3; }
      }
      for (; c < cnt; ++c) {
        int k = cand[tok * MAXC + c];
        float4 ev = *reinterpret_cast<const float4*>(cb + (size_t)k * 256 + lane * 4);
        float dp = zv.x * ev.x + zv.y * ev.y + zv.z * ev.z + zv.w * ev.w;
        #pragma unroll
        for (int off = 32; off; off >>= 1) dp += __shfl_xor(dp, off, 64);
        float s = ee_lds[k] - 2.f * dp;   // identical on all lanes
        if (s < bs || (s == bs && k < bk)) { bs = s; bk = k; }
      }
    }
    bkbuf[tok] = (unsigned short)bk;
  }

  // ---- phase 2: outputs + loss, 2 tokens in flight ----
  float lsum = 0.f, msum = 0.f;
  for (int it = 0; it < 16; it += 2) {
    int tokA = wv * 16 + it, tokB = tokA + 1;
    int na = n0 + tokA, nb = n0 + tokB;
    int ba = bkbuf[tokA], bb = bkbuf[tokB];
    float4 za = *reinterpret_cast<const float4*>(z + (size_t)na * 256 + lane * 4);
    float4 zb = *reinterpret_cast<const float4*>(z + (size_t)nb * 256 + lane * 4);
    float4 qa = *reinterpret_cast<const float4*>(cb + (size_t)ba * 256 + lane * 4);
    float4 qb = *reinterpret_cast<const float4*>(cb + (size_t)bb * 256 + lane * 4);
    float ma = mask[na], mb = mask[nb];
    float4 oa; oa.x = qa.x * ma; oa.y = qa.y * ma; oa.z = qa.z * ma; oa.w = qa.w * ma;
    float4 ob; ob.x = qb.x * mb; ob.y = qb.y * mb; ob.z = qb.z * mb; ob.w = qb.w * mb;
    *reinterpret_cast<float4*>(out_q + (size_t)na * 256 + lane * 4) = oa;
    *reinterpret_cast<float4*>(out_q + (size_t)nb * 256 + lane * 4) = ob;
    float dxa = za.x - qa.x, dya = za.y - qa.y, dza = za.z - qa.z, dwa = za.w - qa.w;
    float dxb = zb.x - qb.x, dyb = zb.y - qb.y, dzb = zb.z - qb.z, dwb = zb.w - qb.w;
    lsum = fmaf(ma, dxa * dxa + dya * dya + dza * dza + dwa * dwa, lsum);
    lsum = fmaf(mb, dxb * dxb + dyb * dyb + dzb * dzb + dwb * dwb, lsum);
    if (lane == 0) {
      msum += ma + mb;
      out_idx_f[na] = (ma > 0.f) ? (float)ba : 0.f;
      out_idx_f[nb] = (mb > 0.f) ? (float)bb : 0.f;
    }
  }
  #pragma unroll
  for (int off = 32; off; off >>= 1) lsum += __shfl_down(lsum, off, 64);
  if (lane == 0) { red[wv] = lsum; red[4 + wv] = msum; }
  __syncthreads();
  if (t == 0) {
    atomicAdd(&acc2[0], red[0] + red[1] + red[2] + red[3]);
    atomicAdd(&acc2[1], red[4] + red[5] + red[6] + red[7]);
    __threadfence();
    int prev = atomicAdd(done_ctr, 1);
    last = (prev == nblocks - 1);
  }
  __syncthreads();
  if (last && t == 0) {
    float s  = atomicAdd(&acc2[0], 0.0f);
    float nv = atomicAdd(&acc2[1], 0.0f);
    out_loss[0] = (nv > 0.f) ? (0.25f * s / (nv * 256.0f)) : 0.0f;
  }
}

// ---------------------------------------------------------------------------
extern "C" void kernel_launch(void* const* d_in, const int* in_sizes, int n_in,
                              void* d_out, int out_size, void* d_ws, size_t ws_size,
                              hipStream_t stream) {
  const float* z    = (const float*)d_in[0];  // (N, 256)
  const float* mask = (const float*)d_in[1];  // (N,)
  const float* cb   = (const float*)d_in[2];  // (K, 256)
  const int N = in_sizes[1];                  // 32768
  const int D = 256;
  const int K = in_sizes[2] / D;              // 1024

  float* wsf  = (float*)d_ws;
  float* acc2 = wsf;                          // 2 floats
  int*   dctr = (int*)(wsf + 2);              // 1 int
  float* ee   = wsf + 8;                      // K floats
  unsigned short* cb_bf = (unsigned short*)(ee + K);  // K*256 bf16

  float* out_q     = (float*)d_out;           // N*D
  float* out_loss  = out_q + (size_t)N * D;   // 1
  float* out_idx_f = out_loss + 1;            // N

  vq_prep<<<(K + 3) / 4, 256, 0, stream>>>(cb, cb_bf, ee, acc2, dctr, K);
  vq_main<<<N / TOK, 256, 0, stream>>>(z, cb, cb_bf, ee, mask, out_q,
                                       out_idx_f, out_loss, acc2, dctr, N / TOK, K);
}